// Round 1
// baseline (218.680 us; speedup 1.0000x reference)
//
#include <hip/hip_runtime.h>
#include <math.h>

#define DIMS 160
#define TX 16
#define TY 10
#define TZ 10
#define RH 7
#define RL 4
#define KH 15
#define KL 9
#define ZH (TZ + 2*RH)   // 24
#define YH (TY + 2*RH)   // 24
#define ZL (TZ + 2*RL)   // 18
#define YL (TY + 2*RL)   // 18
#define ROWLEN 17        // TX + 1 pad (breaks power-of-2 LDS strides)
#define NROWS_H (ZH*YH)  // 576
#define NROWS_L (ZL*YL)  // 324
#define SB_ZS 176        // TY*TX + 16 pad
#define SA_SIZE (NROWS_H*ROWLEN)  // 9792 floats
#define SB_SIZE (ZH*SB_ZS)        // 4224 floats
// total static LDS = 14016 floats = 56,064 B  (<64KB static limit, 2 blocks/CU)

struct DoGW { float gl[KL]; float gh[KH]; };

__device__ __forceinline__ void load_row32(const float* __restrict__ rowp,
                                           int x0, bool xfast, float v[32]) {
    if (xfast) {
        const float4* p4 = (const float4*)(rowp + x0 - 8);  // 16B aligned: x0%16==0
        #pragma unroll
        for (int i = 0; i < 8; ++i) {
            float4 t = p4[i];
            v[4*i+0] = t.x; v[4*i+1] = t.y; v[4*i+2] = t.z; v[4*i+3] = t.w;
        }
    } else {
        #pragma unroll
        for (int i = 0; i < 32; ++i) {
            int xg = min(max(x0 - 8 + i, 0), DIMS - 1);   // replicate padding
            v[i] = rowp[xg];
        }
    }
}

__global__ __launch_bounds__(256, 2)
void dog3d_kernel(const float* __restrict__ X, float* __restrict__ out, DoGW w) {
    __shared__ float sA[SA_SIZE];
    __shared__ float sB[SB_SIZE];

    const int bid = blockIdx.x;
    const int xt = bid % (DIMS/TX);                       // 10
    const int yt = (bid / (DIMS/TX)) % (DIMS/TY);         // 16
    const int zt = (bid / ((DIMS/TX)*(DIMS/TY))) % (DIMS/TZ); // 16
    const int b  = bid / ((DIMS/TX)*(DIMS/TY)*(DIMS/TZ)); // 2
    const int x0 = xt*TX, y0 = yt*TY, z0 = zt*TZ;
    const float* Xb = X + (size_t)b*DIMS*DIMS*DIMS;
    const int tid = threadIdx.x;
    const bool xfast = (x0 >= 8) && (x0 + 24 <= DIMS);

    float acc_h[TZ];

    // ================= HIGH pass (sigma=1.6, K=15) =================
    // ---- W conv: one thread per (z,y) halo row ----
    for (int r = tid; r < NROWS_H; r += 256) {
        int zi = r / YH, yi = r % YH;
        int zg = min(max(z0 + zi - RH, 0), DIMS-1);
        int yg = min(max(y0 + yi - RH, 0), DIMS-1);
        const float* rowp = Xb + ((size_t)zg*DIMS + yg)*DIMS;
        float v[32];
        load_row32(rowp, x0, xfast, v);
        #pragma unroll
        for (int xo = 0; xo < TX; ++xo) {
            float a = 0.f;
            #pragma unroll
            for (int k = 0; k < KH; ++k) a = fmaf(w.gh[k], v[xo + k + 1], a);
            sA[r*ROWLEN + xo] = a;
        }
    }
    __syncthreads();
    // ---- H conv: thread per (z,x) column, sliding window over y ----
    for (int u = tid; u < ZH*TX; u += 256) {   // 384 units
        int z = u >> 4, x = u & 15;
        float win[YH];
        #pragma unroll
        for (int yy = 0; yy < YH; ++yy) win[yy] = sA[(z*YH + yy)*ROWLEN + x];
        #pragma unroll
        for (int y = 0; y < TY; ++y) {
            float a = 0.f;
            #pragma unroll
            for (int k = 0; k < KH; ++k) a = fmaf(w.gh[k], win[y + k], a);
            sB[z*SB_ZS + y*TX + x] = a;
        }
    }
    __syncthreads();
    // ---- D conv: thread per (y,x), accumulate 10 z outputs in regs ----
    if (tid < TY*TX) {   // 160 threads
        int y = tid >> 4, x = tid & 15;
        float win[ZH];
        #pragma unroll
        for (int zz = 0; zz < ZH; ++zz) win[zz] = sB[zz*SB_ZS + y*TX + x];
        #pragma unroll
        for (int z = 0; z < TZ; ++z) {
            float a = 0.f;
            #pragma unroll
            for (int k = 0; k < KH; ++k) a = fmaf(w.gh[k], win[z + k], a);
            acc_h[z] = a;
        }
    }

    // ================= LOW pass (sigma=1.0, K=9), reusing sA/sB =================
    // No barrier needed before W-low: sA readers (H-high) all passed the
    // barrier above; D-high touches only sB.
    for (int r = tid; r < NROWS_L; r += 256) {
        int zi = r / YL, yi = r % YL;
        int zg = min(max(z0 + zi - RL, 0), DIMS-1);
        int yg = min(max(y0 + yi - RL, 0), DIMS-1);
        const float* rowp = Xb + ((size_t)zg*DIMS + yg)*DIMS;
        float v[32];
        load_row32(rowp, x0, xfast, v);
        #pragma unroll
        for (int xo = 0; xo < TX; ++xo) {
            float a = 0.f;
            #pragma unroll
            for (int k = 0; k < KL; ++k) a = fmaf(w.gl[k], v[xo + k + 4], a);
            sA[r*ROWLEN + xo] = a;
        }
    }
    __syncthreads();   // also guarantees D-high finished reading sB
    for (int u = tid; u < ZL*TX; u += 256) {   // 288 units
        int z = u >> 4, x = u & 15;
        float win[YL];
        #pragma unroll
        for (int yy = 0; yy < YL; ++yy) win[yy] = sA[(z*YL + yy)*ROWLEN + x];
        #pragma unroll
        for (int y = 0; y < TY; ++y) {
            float a = 0.f;
            #pragma unroll
            for (int k = 0; k < KL; ++k) a = fmaf(w.gl[k], win[y + k], a);
            sB[z*SB_ZS + y*TX + x] = a;
        }
    }
    __syncthreads();
    if (tid < TY*TX) {
        int y = tid >> 4, x = tid & 15;
        float win[ZL];
        #pragma unroll
        for (int zz = 0; zz < ZL; ++zz) win[zz] = sB[zz*SB_ZS + y*TX + x];
        #pragma unroll
        for (int z = 0; z < TZ; ++z) {
            float a = 0.f;
            #pragma unroll
            for (int k = 0; k < KL; ++k) a = fmaf(w.gl[k], win[z + k], a);
            // DoG = low_pass - high_pass
            size_t o = (((size_t)(b*DIMS + z0 + z))*DIMS + (y0 + y))*DIMS + (x0 + x);
            out[o] = a - acc_h[z];
        }
    }
}

extern "C" void kernel_launch(void* const* d_in, const int* in_sizes, int n_in,
                              void* d_out, int out_size, void* d_ws, size_t ws_size,
                              hipStream_t stream) {
    const float* X = (const float*)d_in[0];
    float* out = (float*)d_out;

    DoGW w;
    {
        double s = 0.0;
        for (int i = 0; i < KL; ++i) {
            double t = i - (KL - 1) / 2.0;
            double g = exp(-(t*t) / (2.0 * 1.0 * 1.0));
            w.gl[i] = (float)g; s += g;
        }
        for (int i = 0; i < KL; ++i) w.gl[i] = (float)((double)w.gl[i] / s);
        s = 0.0;
        for (int i = 0; i < KH; ++i) {
            double t = i - (KH - 1) / 2.0;
            double g = exp(-(t*t) / (2.0 * 1.6 * 1.6));
            w.gh[i] = (float)g; s += g;
        }
        for (int i = 0; i < KH; ++i) w.gh[i] = (float)((double)w.gh[i] / s);
    }

    const int nblocks = (DIMS/TX) * (DIMS/TY) * (DIMS/TZ) * 2;  // 5120
    dog3d_kernel<<<nblocks, 256, 0, stream>>>(X, out, w);
}

// Round 2
// 196.670 us; speedup vs baseline: 1.1119x; 1.1119x over previous
//
#include <hip/hip_runtime.h>
#include <math.h>

#define DIMS 160
#define TS 16              // xy tile
#define CZ 40              // z outputs per block
#define NCH (DIMS/CZ)      // 4 z-chunks
#define RH 7
#define RL 4
#define KH 15
#define KL 9
#define YHR (TS + 2*RH)    // 30 y-halo rows (high)
#define YLR (TS + 2*RL)    // 24 y-halo rows (low)
#define RS 36              // raw plane row stride in floats (32 data + 4 pad; breaks 128B bank wrap)
#define XS 20              // x-conv output row stride (16 data + 4 pad; 16B-aligned, 2-way banks)
#define NSTEPS (CZ + 2*RH) // 54 planes marched per block

struct DoGW { float gl[KL]; float gh[KH]; };

// z-marching slab: block = 16x16 (x,y) tile, marches 54 z-planes.
// Per step: load halo plane (float4/thread, double-buffered) -> x-conv
// (ds_read_b128 windows) -> y-conv + z accumulator-scatter in registers.
// accH[i]/accL[i] hold pending output z = zp-7+i; plane zp contributes
// wh[14-i] (all i) and wl[11-i] (i=3..11); accH[0]/accL[0] retire each step.
__global__ __launch_bounds__(256, 4)
void dog3d_zmarch(const float* __restrict__ X, float* __restrict__ out, DoGW w) {
  __shared__ float sRaw[2][YHR * RS];  // 2*1080 floats
  __shared__ float sXh[YHR * XS];      // 600
  __shared__ float sXl[YLR * XS];      // 480   -> total 12,960 B LDS

  const int NT = DIMS / TS;            // 10
  const int bid = blockIdx.x;
  const int xt = bid % NT;
  const int yt = (bid / NT) % NT;
  const int zc = (bid / (NT * NT)) % NCH;
  const int b  = bid / (NT * NT * NCH);
  const int x0 = xt * TS, y0 = yt * TS, z0 = zc * CZ;
  const float* Xb = X + (size_t)b * (DIMS * DIMS * DIMS);
  const int tid = threadIdx.x;
  const bool xfast = (x0 >= 8) && (x0 + 24 <= DIMS);  // interior x-tiles: aligned float4 path

  // Phase A (plane load): 240 units = 30 rows x 8 quads
  const bool a_on = tid < YHR * 8;
  const int ar = tid >> 3, aq = tid & 7;
  const int aygl = min(max(y0 + ar - RH, 0), DIMS - 1);
  const int acol0 = x0 - 8 + aq * 4;

  // Phase B (x-conv): high 120 units (30 rows x 4 xquads), low 96 units (24 x 4)
  const bool bh_on = tid < 120;
  const int bhr = tid >> 2, bhq = tid & 3;
  const bool bl_on = (tid >= 120) && (tid < 216);
  const int blr = (tid - 120) >> 2, blq = (tid - 120) & 3;

  // Phase C (y-conv + z-scatter): all 256 threads, one (y,x) each
  const int cy = tid >> 4, cx = tid & 15;

  float accH[KH];
  float accL[KL + 3];   // low retires 3 steps late; buffer the gap
  #pragma unroll
  for (int i = 0; i < KH; ++i) accH[i] = 0.f;
  #pragma unroll
  for (int i = 0; i < KL + 3; ++i) accL[i] = 0.f;

  auto loadA = [&](int p, int buf) {
    if (!a_on) return;
    const int zsrc = min(max(z0 - RH + p, 0), DIMS - 1);   // replicate in z
    const float* rowp = Xb + ((size_t)zsrc * DIMS + aygl) * DIMS;
    float4 v;
    if (xfast) {
      v = *(const float4*)(rowp + acol0);
    } else {
      v.x = rowp[min(max(acol0 + 0, 0), DIMS - 1)];
      v.y = rowp[min(max(acol0 + 1, 0), DIMS - 1)];
      v.z = rowp[min(max(acol0 + 2, 0), DIMS - 1)];
      v.w = rowp[min(max(acol0 + 3, 0), DIMS - 1)];
    }
    *(float4*)&sRaw[buf][ar * RS + aq * 4] = v;
  };

  loadA(0, 0);

  for (int p = 0; p < NSTEPS; ++p) {
    const int cur = p & 1;
    __syncthreads();                       // raw[cur] ready; sX free; raw[1-cur] free
    if (p + 1 < NSTEPS) loadA(p + 1, 1 - cur);  // prefetch next plane into other buffer

    if (bh_on) {                           // x-conv, high (K=15)
      float win[20];
      #pragma unroll
      for (int t = 0; t < 5; ++t)
        *(float4*)&win[4 * t] = *(const float4*)&sRaw[cur][bhr * RS + bhq * 4 + 4 * t];
      float o[4];
      #pragma unroll
      for (int c = 0; c < 4; ++c) {
        float a = 0.f;
        #pragma unroll
        for (int k = 0; k < KH; ++k) a = fmaf(w.gh[k], win[c + 1 + k], a);
        o[c] = a;
      }
      *(float4*)&sXh[bhr * XS + bhq * 4] = make_float4(o[0], o[1], o[2], o[3]);
    }
    if (bl_on) {                           // x-conv, low (K=9); raw row offset +3 (RH-RL)
      float win[12];
      #pragma unroll
      for (int t = 0; t < 3; ++t)
        *(float4*)&win[4 * t] = *(const float4*)&sRaw[cur][(blr + 3) * RS + blq * 4 + 4 + 4 * t];
      float o[4];
      #pragma unroll
      for (int c = 0; c < 4; ++c) {
        float a = 0.f;
        #pragma unroll
        for (int k = 0; k < KL; ++k) a = fmaf(w.gl[k], win[c + k], a);
        o[c] = a;
      }
      *(float4*)&sXl[blr * XS + blq * 4] = make_float4(o[0], o[1], o[2], o[3]);
    }
    __syncthreads();                       // sX ready

    float ph = 0.f, pl = 0.f;              // y-conv
    #pragma unroll
    for (int j = 0; j < KH; ++j) ph = fmaf(w.gh[j], sXh[(cy + j) * XS + cx], ph);
    #pragma unroll
    for (int j = 0; j < KL; ++j) pl = fmaf(w.gl[j], sXl[(cy + j) * XS + cx], pl);

    #pragma unroll                         // z accumulator-scatter
    for (int i = 0; i < KH; ++i) accH[i] = fmaf(w.gh[KH - 1 - i], ph, accH[i]);
    #pragma unroll
    for (int i = 3; i < KL + 3; ++i) accL[i] = fmaf(w.gl[KL + 2 - i], pl, accL[i]);

    if (p >= 2 * RH) {                     // retire output z = z0 + p - 14
      const int zo = z0 + p - 2 * RH;
      const size_t o = (((size_t)(b * DIMS + zo)) * DIMS + (y0 + cy)) * DIMS + (x0 + cx);
      out[o] = accL[0] - accH[0];          // DoG = low - high
    }
    #pragma unroll
    for (int i = 0; i < KH - 1; ++i) accH[i] = accH[i + 1];
    accH[KH - 1] = 0.f;
    #pragma unroll
    for (int i = 0; i < KL + 2; ++i) accL[i] = accL[i + 1];
    accL[KL + 2] = 0.f;
  }
}

extern "C" void kernel_launch(void* const* d_in, const int* in_sizes, int n_in,
                              void* d_out, int out_size, void* d_ws, size_t ws_size,
                              hipStream_t stream) {
  const float* X = (const float*)d_in[0];
  float* out = (float*)d_out;

  DoGW w;
  {
    double s = 0.0;
    for (int i = 0; i < KL; ++i) {
      double t = i - (KL - 1) / 2.0;
      double g = exp(-(t * t) / (2.0 * 1.0 * 1.0));
      w.gl[i] = (float)g; s += g;
    }
    for (int i = 0; i < KL; ++i) w.gl[i] = (float)((double)w.gl[i] / s);
    s = 0.0;
    for (int i = 0; i < KH; ++i) {
      double t = i - (KH - 1) / 2.0;
      double g = exp(-(t * t) / (2.0 * 1.6 * 1.6));
      w.gh[i] = (float)g; s += g;
    }
    for (int i = 0; i < KH; ++i) w.gh[i] = (float)((double)w.gh[i] / s);
  }

  const int nblocks = (DIMS / TS) * (DIMS / TS) * NCH * 2;  // 10*10*4*2 = 800
  dog3d_zmarch<<<nblocks, 256, 0, stream>>>(X, out, w);
}